// Round 17
// baseline (8044.292 us; speedup 1.0000x reference)
//
#include <hip/hip_runtime.h>
#include <stdint.h>

#define B_    32
#define S_    1024
#define HIN   1024
#define NBLK  64
#define DBLK  16
#define HOUT  1024
#define NGATE 1152   // 64 i + 64 o + 1024 g
#define NSLICE 32    // gate slices (32 Ug rows + 2 Ui + 2 Uo each)

typedef __attribute__((ext_vector_type(8))) __bf16 bf16x8;
typedef __attribute__((ext_vector_type(4))) float  f32x4;
typedef __attribute__((ext_vector_type(4))) unsigned int u32x4;

__device__ __forceinline__ unsigned short f2bf(float f) {
    union { float f; unsigned u; } v; v.f = f;
    return (unsigned short)((v.u + 0x7fffu + ((v.u >> 16) & 1u)) >> 16);
}
__device__ __forceinline__ float bf2f(unsigned short h) {
    union { unsigned u; float f; } v; v.u = ((unsigned)h) << 16; return v.f;
}
// fp32 -> hi+lo bf16 (v ~= hi + lo, residual <= 2^-18 |v|)
__device__ __forceinline__ void split1(float f, unsigned short& hi, unsigned short& lo) {
    hi = f2bf(f);
    lo = f2bf(f - bf2f(hi));
}

// gate-row mapping for a slice: rows 0..31 = Ug[slice*32+r], 32..33 = Ui[2s..], 34..35 = Uo[2s..]
__device__ __forceinline__ int slice_row(int slice, int r) {
    return (r < 32) ? (128 + slice * 32 + r)
         : (r < 34) ? (slice * 2 + (r - 32))
                    : (64 + slice * 2 + (r - 34));
}

// hbuf fragment-native layout (per plane):
//   [slot:2][group:2][colblk:128][row:16][j:8] bf16
//   slot stride 32768 shorts, group stride 16384, colblk stride 128, row stride 8.
// Consumer lane (l15,l4) of wave w, k-block ks reads 16B unit (colblk=w*32+ks*4+l4, row=l15)
// == A-fragment cols w*256+ks*32+l4*8 .. +8 of batch row l15. Coalesced dwordx4.

// ---------------- phase 0: split W,U into hi/lo bf16; split h0 into planes ----------------
__global__ void k_init(const float* __restrict__ Wi, const float* __restrict__ Wo,
                       const float* __restrict__ Wg,
                       const float* __restrict__ Ui, const float* __restrict__ Uo,
                       const float* __restrict__ Ug, const float* __restrict__ h0,
                       unsigned short* __restrict__ WsH, unsigned short* __restrict__ WsL,
                       unsigned short* __restrict__ UsH, unsigned short* __restrict__ UsL,
                       unsigned short* __restrict__ hbH, unsigned short* __restrict__ hbL)
{
    int idx = blockIdx.x * 256 + threadIdx.x;
    const int nW = NGATE * HOUT / 4;           // 294912 quads per matrix set
    float4 v; unsigned short *dH, *dL;
    if (idx < nW) {
        int f = idx * 4; int row = f >> 10, k = f & 1023;
        const float* src = (row < 64)  ? (Wi + (size_t)row * HIN)
                         : (row < 128) ? (Wo + (size_t)(row - 64) * HIN)
                                       : (Wg + (size_t)(row - 128) * HIN);
        v = *(const float4*)(src + k);
        dH = WsH + f; dL = WsL + f;
    } else if (idx < 2 * nW) {
        int f = (idx - nW) * 4; int row = f >> 10, k = f & 1023;
        const float* src = (row < 64)  ? (Ui + (size_t)row * HOUT)
                         : (row < 128) ? (Uo + (size_t)(row - 64) * HOUT)
                                       : (Ug + (size_t)(row - 128) * HOUT);
        v = *(const float4*)(src + k);
        dH = UsH + f; dL = UsL + f;
    } else {
        int f = (idx - 2 * nW) * 4;
        if (f >= B_ * HOUT) return;
        v = *(const float4*)(h0 + f);
        int b = f >> 10, c = f & 1023;
        int g = b >> 4, r = b & 15;
        int off = g * 16384 + (c >> 3) * 128 + r * 8 + (c & 7);   // slot 0
        dH = hbH + off; dL = hbL + off;
    }
    unsigned short th[4], tl[4];
    split1(v.x, th[0], tl[0]); split1(v.y, th[1], tl[1]);
    split1(v.z, th[2], tl[2]); split1(v.w, th[3], tl[3]);
    *(uint2*)dH = *(const uint2*)th;
    *(uint2*)dL = *(const uint2*)tl;
}

// ---------------- phase 1: gate pre-projection GEMM (bf16x3) ----------------
#define BM 128
#define BN 128
#define BK 32
#define LDP 56

__global__ __launch_bounds__(256) void k_gates(
    const float* __restrict__ x,
    const unsigned short* __restrict__ WsH, const unsigned short* __restrict__ WsL,
    const float* __restrict__ bi, const float* __restrict__ bo, const float* __restrict__ bg,
    float* __restrict__ c_out, float* __restrict__ h_out)
{
    __shared__ unsigned short AlH[BM][LDP], AlL[BM][LDP];
    __shared__ unsigned short BlH[BN][LDP], BlL[BN][LDP];
    const int tid  = threadIdx.x;
    const int bm   = blockIdx.x, bn = blockIdx.y;
    const int wave = tid >> 6,  lane = tid & 63;
    const int l15  = lane & 15, l4 = lane >> 4;
    const int wm   = wave >> 1, wn = wave & 1;
    const int rbase = tid >> 3;          // 0..31
    const int c4    = (tid & 7) * 4;     // 0..28

    f32x4 acc[4][4] = {};

    for (int kk = 0; kk < HIN; kk += BK) {
        #pragma unroll
        for (int i = 0; i < 4; ++i) {
            int row = rbase + 32 * i;
            float4 v = *(const float4*)(x + (size_t)(bm * BM + row) * HIN + kk + c4);
            unsigned short th[4], tl[4];
            split1(v.x, th[0], tl[0]); split1(v.y, th[1], tl[1]);
            split1(v.z, th[2], tl[2]); split1(v.w, th[3], tl[3]);
            *(uint2*)&AlH[row][c4] = *(const uint2*)th;
            *(uint2*)&AlL[row][c4] = *(const uint2*)tl;
            int n = bn * BN + row;
            *(uint2*)&BlH[row][c4] = *(const uint2*)(WsH + (size_t)n * HIN + kk + c4);
            *(uint2*)&BlL[row][c4] = *(const uint2*)(WsL + (size_t)n * HIN + kk + c4);
        }
        __syncthreads();
        uint4 ah[4], al[4], bh4[4], bl4[4];
        #pragma unroll
        for (int mi = 0; mi < 4; ++mi) {
            ah[mi] = *(const uint4*)&AlH[wm * 64 + mi * 16 + l15][l4 * 8];
            al[mi] = *(const uint4*)&AlL[wm * 64 + mi * 16 + l15][l4 * 8];
        }
        #pragma unroll
        for (int ni = 0; ni < 4; ++ni) {
            bh4[ni] = *(const uint4*)&BlH[wn * 64 + ni * 16 + l15][l4 * 8];
            bl4[ni] = *(const uint4*)&BlL[wn * 64 + ni * 16 + l15][l4 * 8];
        }
        #pragma unroll
        for (int mi = 0; mi < 4; ++mi) {
            #pragma unroll
            for (int ni = 0; ni < 4; ++ni) {
                acc[mi][ni] = __builtin_amdgcn_mfma_f32_16x16x32_bf16(
                    __builtin_bit_cast(bf16x8, ah[mi]), __builtin_bit_cast(bf16x8, bh4[ni]),
                    acc[mi][ni], 0, 0, 0);
                acc[mi][ni] = __builtin_amdgcn_mfma_f32_16x16x32_bf16(
                    __builtin_bit_cast(bf16x8, ah[mi]), __builtin_bit_cast(bf16x8, bl4[ni]),
                    acc[mi][ni], 0, 0, 0);
                acc[mi][ni] = __builtin_amdgcn_mfma_f32_16x16x32_bf16(
                    __builtin_bit_cast(bf16x8, al[mi]), __builtin_bit_cast(bf16x8, bh4[ni]),
                    acc[mi][ni], 0, 0, 0);
            }
        }
        __syncthreads();
    }

    #pragma unroll
    for (int ni = 0; ni < 4; ++ni) {
        int n = bn * BN + wn * 64 + ni * 16 + l15;
        float bv = (n < 64) ? bi[n] : (n < 128) ? bo[n - 64] : bg[n - 128];
        #pragma unroll
        for (int mi = 0; mi < 4; ++mi) {
            #pragma unroll
            for (int r = 0; r < 4; ++r) {
                int m = bm * BM + wm * 64 + mi * 16 + l4 * 4 + r;
                float val = acc[mi][ni][r] + bv;
                if (n >= 128) {
                    h_out[(size_t)m * HOUT + (n - 128)] = val;
                } else if (n < 64) {
                    c_out[((size_t)m * NBLK + n) * DBLK + 0] = val;
                } else {
                    c_out[((size_t)m * NBLK + (n - 64)) * DBLK + 1] = val;
                }
            }
        }
    }
}

// ---------------- phase 2: persistent lockstep recurrence (bf16x3) ----------------
// 64 WGs x 256 thr. slice = bid&31, group = bid>>5 (batches [16g,+16)).
// R17 = R16 sync skeleton + fragment-native hbuf:
//  * A-fragments load DIRECTLY from LLC as coalesced dwordx4 (16B units laid out
//    per (colblk,row)) -- zero LDS round-trip for A, 16 loads/lane (was 32), one drain.
//  * U-lo streams from L2 in-loop like U-hi (no Wlo LDS; invalid rows write
//    preW cols 36..47 which the epilogue never reads -> no masking needed).
//  * LDS = preW only (13.6 KB). R16 flags/poll/output/prefetch placement verbatim.
__global__ __launch_bounds__(256, 1) void k_rec(
    const float* __restrict__ c0,
    float* __restrict__ c_out, float* __restrict__ h_out,
    const unsigned short* __restrict__ UsH, const unsigned short* __restrict__ UsL,
    unsigned short* __restrict__ hbH, unsigned short* __restrict__ hbL,
    unsigned int* __restrict__ flags)
{
    __shared__ float preW[4][16][53];          // 13.6 KB per-wave partials (pad 53)

    const int tid   = threadIdx.x;
    const int slice = blockIdx.x & 31;
    const int group = blockIdx.x >> 5;     // 0 or 1
    const int wave  = tid >> 6, lane = tid & 63;
    const int l15   = lane & 15, l4 = lane >> 4;

    // weight row pointers for this wave's K-quarter (streamed from L2 each step;
    // rows for grow>=36 clamp to row 0 -- their products land in unread preW cols)
    const unsigned short* phh[3];
    const unsigned short* phl[3];
    #pragma unroll
    for (int nt = 0; nt < 3; ++nt) {
        int grow = nt * 16 + l15;
        int srow = (grow < 36) ? slice_row(slice, grow) : 0;
        phh[nt] = UsH + (size_t)srow * HOUT + wave * 256 + l4 * 8;
        phl[nt] = UsL + (size_t)srow * HOUT + wave * 256 + l4 * 8;
    }

    // per-thread epilogue mapping: 2 consecutive h-cols
    const int e0   = tid * 2;
    const int bl   = e0 >> 5;             // 0..15 batch-in-group
    const int col0 = e0 & 31;             // even
    const int Bg   = group * 16 + bl;
    const int hcol = slice * 32 + col0;
    const int blkI = hcol >> 4, d0 = hcol & 15;
    float cr0 = c0[((size_t)Bg * NBLK + blkI) * DBLK + d0];
    float cr1 = c0[((size_t)Bg * NBLK + blkI) * DBLK + d0 + 1];

    // publish offset (shorts) within a slot: group/colblk/row/j
    const int puboff = group * 16384 + (slice * 4 + (col0 >> 3)) * 128 + bl * 8 + (col0 & 7);

    unsigned int* flagbase = flags + (size_t)group * NSLICE * 32;
    unsigned int* myflag   = flagbase + slice * 32 + wave;            // quarter-flag dword
    unsigned long long* pollp =
        (unsigned long long*)(flagbase + (lane & 31) * 32 + 2 * (lane >> 5));

    // A-load base (bytes): unit (colblk = wave*32 + l4, row = l15); ks stride 1024B
    const int abase = ((wave * 32 + l4) * 128 + l15 * 8);   // shorts, within group plane

    // step-0 gate preactivation prefetch
    float xg0, xg1, xi, xo;
    {
        size_t r0 = (size_t)Bg * S_;
        xg0 = h_out[r0 * HOUT + hcol];
        xg1 = h_out[r0 * HOUT + hcol + 1];
        xi  = c_out[(r0 * NBLK + blkI) * DBLK + 0];
        xo  = c_out[(r0 * NBLK + blkI) * DBLK + 1];
    }

    for (int t = 0; t < S_; ++t) {
        // ---- 1. poll (wave 0 only; 64 lanes x 8B cover all 128 quarter-flags)
        if (t > 0) {
            if (wave == 0) {
                unsigned long long v;
                do {
                    v = __hip_atomic_load(pollp, __ATOMIC_RELAXED, __HIP_MEMORY_SCOPE_AGENT);
                } while (!__all((int)((unsigned)v >= (unsigned)t &&
                                      (unsigned)(v >> 32) >= (unsigned)t)));
            }
            __syncthreads();
        }

        // ---- 2. A-fragments straight from LLC: 16 coalesced dwordx4, one drain
        u32x4 ah[8], al[8];
        {
            const char* pH = (const char*)(hbH + (size_t)(t & 1) * 32768
                                           + group * 16384 + abase);
            const char* pL = (const char*)(hbL + (size_t)(t & 1) * 32768
                                           + group * 16384 + abase);
            asm volatile(
                "global_load_dwordx4 %0, %16, off sc0 sc1\n\t"
                "global_load_dwordx4 %1, %16, off offset:1024 sc0 sc1\n\t"
                "global_load_dwordx4 %2, %16, off offset:2048 sc0 sc1\n\t"
                "global_load_dwordx4 %3, %16, off offset:3072 sc0 sc1\n\t"
                "global_load_dwordx4 %4, %17, off sc0 sc1\n\t"
                "global_load_dwordx4 %5, %17, off offset:1024 sc0 sc1\n\t"
                "global_load_dwordx4 %6, %17, off offset:2048 sc0 sc1\n\t"
                "global_load_dwordx4 %7, %17, off offset:3072 sc0 sc1\n\t"
                "global_load_dwordx4 %8, %18, off sc0 sc1\n\t"
                "global_load_dwordx4 %9, %18, off offset:1024 sc0 sc1\n\t"
                "global_load_dwordx4 %10, %18, off offset:2048 sc0 sc1\n\t"
                "global_load_dwordx4 %11, %18, off offset:3072 sc0 sc1\n\t"
                "global_load_dwordx4 %12, %19, off sc0 sc1\n\t"
                "global_load_dwordx4 %13, %19, off offset:1024 sc0 sc1\n\t"
                "global_load_dwordx4 %14, %19, off offset:2048 sc0 sc1\n\t"
                "global_load_dwordx4 %15, %19, off offset:3072 sc0 sc1\n\t"
                "s_waitcnt vmcnt(0)\n\t"
                : "=&v"(ah[0]), "=&v"(ah[1]), "=&v"(ah[2]), "=&v"(ah[3]),
                  "=&v"(ah[4]), "=&v"(ah[5]), "=&v"(ah[6]), "=&v"(ah[7]),
                  "=&v"(al[0]), "=&v"(al[1]), "=&v"(al[2]), "=&v"(al[3]),
                  "=&v"(al[4]), "=&v"(al[5]), "=&v"(al[6]), "=&v"(al[7])
                : "v"(pH), "v"(pH + 4096), "v"(pL), "v"(pL + 4096)
                : "memory");
            __builtin_amdgcn_sched_barrier(0);
        }

        // ---- 3. next-step prefetch (retires during MFMA phase)
        float nxg0 = 0.f, nxg1 = 0.f, nxi = 0.f, nxo = 0.f;
        if (t + 1 < S_) {
            size_t rn = (size_t)Bg * S_ + (t + 1);
            nxg0 = h_out[rn * HOUT + hcol];
            nxg1 = h_out[rn * HOUT + hcol + 1];
            nxi  = c_out[(rn * NBLK + blkI) * DBLK + 0];
            nxo  = c_out[(rn * NBLK + blkI) * DBLK + 1];
        }

        // ---- 4. K-split MFMA: all 36 gate rows over MY quarter; weights stream
        //         from L2 in-loop (compiler schedules the loads ahead)
        f32x4 acc[3] = {};
        #pragma unroll
        for (int ks = 0; ks < 8; ++ks) {
            #pragma unroll
            for (int nt = 0; nt < 3; ++nt) {
                u32x4 bh = *(const u32x4*)(phh[nt] + ks * 32);
                u32x4 blv = *(const u32x4*)(phl[nt] + ks * 32);
                acc[nt] = __builtin_amdgcn_mfma_f32_16x16x32_bf16(
                        __builtin_bit_cast(bf16x8, ah[ks]), __builtin_bit_cast(bf16x8, bh), acc[nt], 0, 0, 0);
                acc[nt] = __builtin_amdgcn_mfma_f32_16x16x32_bf16(
                        __builtin_bit_cast(bf16x8, al[ks]), __builtin_bit_cast(bf16x8, bh), acc[nt], 0, 0, 0);
                acc[nt] = __builtin_amdgcn_mfma_f32_16x16x32_bf16(
                        __builtin_bit_cast(bf16x8, ah[ks]), __builtin_bit_cast(bf16x8, blv), acc[nt], 0, 0, 0);
            }
        }

        // ---- 5. per-wave partials to LDS (plain writes; cols 36..47 unread)
        #pragma unroll
        for (int nt = 0; nt < 3; ++nt) {
            #pragma unroll
            for (int r = 0; r < 4; ++r)
                preW[wave][l4 * 4 + r][nt * 16 + l15] = acc[nt][r];
        }
        __syncthreads();   // [A] all quarters in LDS

        // ---- 6. epilogue: sum 4 wave-partials + prefetched xg/xi/xo
        float gp0 = xg0, gp1 = xg1, ip = xi, op = xo;
        #pragma unroll
        for (int w = 0; w < 4; ++w) {
            gp0 += preW[w][bl][col0];
            gp1 += preW[w][bl][col0 + 1];
            ip  += preW[w][bl][32 + (col0 >> 4)];
            op  += preW[w][bl][34 + (col0 >> 4)];
        }
        float ig  = 1.f / (1.f + __expf(-ip));
        float og  = 1.f / (1.f + __expf(-op));
        cr0 += ig * tanhf(gp0);
        cr1 += ig * tanhf(gp1);
        float h0v = og * tanhf(cr0);
        float h1v = og * tanhf(cr1);

        // ---- 7. publish h_{t+1} (fragment-native layout) -> per-wave drain -> flag
        unsigned short h0h, h0l, h1h, h1l;
        split1(h0v, h0h, h0l); split1(h1v, h1h, h1l);
        size_t dsto = (size_t)((t + 1) & 1) * 32768 + puboff;
        __hip_atomic_store((unsigned int*)(hbH + dsto),
                           (unsigned)h0h | ((unsigned)h1h << 16),
                           __ATOMIC_RELAXED, __HIP_MEMORY_SCOPE_AGENT);
        __hip_atomic_store((unsigned int*)(hbL + dsto),
                           (unsigned)h0l | ((unsigned)h1l << 16),
                           __ATOMIC_RELAXED, __HIP_MEMORY_SCOPE_AGENT);

        asm volatile("s_waitcnt vmcnt(0)" ::: "memory");   // per-wave: own publishes only
        if (lane == 0)
            __hip_atomic_store(myflag, (unsigned)(t + 1),
                               __ATOMIC_RELAXED, __HIP_MEMORY_SCOPE_AGENT);

        // ---- 8. outputs AFTER the flag (RFO latency overlaps next poll)
        size_t ro = (size_t)Bg * S_ + t;
        c_out[(ro * NBLK + blkI) * DBLK + d0]     = cr0;
        c_out[(ro * NBLK + blkI) * DBLK + d0 + 1] = cr1;
        h_out[ro * HOUT + hcol]     = h0v;
        h_out[ro * HOUT + hcol + 1] = h1v;

        // ---- 9. rotate prefetched gate preactivations
        xg0 = nxg0; xg1 = nxg1; xi = nxi; xo = nxo;
    }
}

// ---------------- launch ----------------
extern "C" void kernel_launch(void* const* d_in, const int* in_sizes, int n_in,
                              void* d_out, int out_size, void* d_ws, size_t ws_size,
                              hipStream_t stream) {
    const float* x  = (const float*)d_in[0];
    const float* h0 = (const float*)d_in[1];
    const float* c0 = (const float*)d_in[2];
    const float* Wi = (const float*)d_in[3];
    const float* bi = (const float*)d_in[4];
    const float* Wo = (const float*)d_in[5];
    const float* bo = (const float*)d_in[6];
    const float* Wg = (const float*)d_in[7];
    const float* bg = (const float*)d_in[8];
    const float* Ui = (const float*)d_in[9];
    const float* Uo = (const float*)d_in[10];
    const float* Ug = (const float*)d_in[11];

    float* c_out = (float*)d_out;
    float* h_out = c_out + (size_t)B_ * S_ * NBLK * DBLK;

    unsigned short* WsH  = (unsigned short*)d_ws;                    // [1152][1024]
    unsigned short* WsL  = WsH + (size_t)NGATE * HOUT;
    unsigned short* UsH  = WsL + (size_t)NGATE * HOUT;
    unsigned short* UsL  = UsH + (size_t)NGATE * HOUT;
    unsigned short* hbH  = UsL + (size_t)NGATE * HOUT;               // [2][2][128][16][8]
    unsigned short* hbL  = hbH + (size_t)2 * B_ * HOUT;
    unsigned int*   flags = (unsigned int*)(hbL + (size_t)2 * B_ * HOUT); // [2][32]x128B

    hipMemsetAsync(flags, 0, 64 * 32 * sizeof(unsigned int), stream);
    k_init<<<2336, 256, 0, stream>>>(Wi, Wo, Wg, Ui, Uo, Ug, h0, WsH, WsL, UsH, UsL, hbH, hbL);
    k_gates<<<dim3((B_ * S_) / BM, NGATE / BN), 256, 0, stream>>>(
        x, WsH, WsL, bi, bo, bg, c_out, h_out);
    k_rec<<<64, 256, 0, stream>>>(c0, c_out, h_out, UsH, UsL, hbH, hbL, flags);
}

// Round 19
// 3787.588 us; speedup vs baseline: 2.1239x; 2.1239x over previous
//
#include <hip/hip_runtime.h>
#include <stdint.h>

#define B_    32
#define S_    1024
#define HIN   1024
#define NBLK  64
#define DBLK  16
#define HOUT  1024
#define NGATE 1152   // 64 i + 64 o + 1024 g
#define NSLICE 32    // gate slices (32 Ug rows + 2 Ui + 2 Uo each)

typedef __attribute__((ext_vector_type(8))) __bf16 bf16x8;
typedef __attribute__((ext_vector_type(4))) float  f32x4;
typedef __attribute__((ext_vector_type(4))) unsigned int u32x4;

__device__ __forceinline__ unsigned short f2bf(float f) {
    union { float f; unsigned u; } v; v.f = f;
    return (unsigned short)((v.u + 0x7fffu + ((v.u >> 16) & 1u)) >> 16);
}
__device__ __forceinline__ float bf2f(unsigned short h) {
    union { unsigned u; float f; } v; v.u = ((unsigned)h) << 16; return v.f;
}
// fp32 -> hi+lo bf16 (v ~= hi + lo, residual <= 2^-18 |v|)
__device__ __forceinline__ void split1(float f, unsigned short& hi, unsigned short& lo) {
    hi = f2bf(f);
    lo = f2bf(f - bf2f(hi));
}

// gate-row mapping for a slice: rows 0..31 = Ug[slice*32+r], 32..33 = Ui[2s..], 34..35 = Uo[2s..]
__device__ __forceinline__ int slice_row(int slice, int r) {
    return (r < 32) ? (128 + slice * 32 + r)
         : (r < 34) ? (slice * 2 + (r - 32))
                    : (64 + slice * 2 + (r - 34));
}

// hbuf fragment-native layout (per plane):
//   [slot:2][group:2][colblk:128][row:16][j:8] bf16
// Consumer lane (l15,l4) of wave w, k-block ks reads 16B unit (colblk=w*32+ks*4+l4, row=l15)
// == A-fragment cols w*256+ks*32+l4*8 .. +8 of batch row l15. Coalesced dwordx4.

// ---------------- phase 0: split W,U into hi/lo bf16; split h0 into planes ----------------
__global__ void k_init(const float* __restrict__ Wi, const float* __restrict__ Wo,
                       const float* __restrict__ Wg,
                       const float* __restrict__ Ui, const float* __restrict__ Uo,
                       const float* __restrict__ Ug, const float* __restrict__ h0,
                       unsigned short* __restrict__ WsH, unsigned short* __restrict__ WsL,
                       unsigned short* __restrict__ UsH, unsigned short* __restrict__ UsL,
                       unsigned short* __restrict__ hbH, unsigned short* __restrict__ hbL)
{
    int idx = blockIdx.x * 256 + threadIdx.x;
    const int nW = NGATE * HOUT / 4;           // 294912 quads per matrix set
    float4 v; unsigned short *dH, *dL;
    if (idx < nW) {
        int f = idx * 4; int row = f >> 10, k = f & 1023;
        const float* src = (row < 64)  ? (Wi + (size_t)row * HIN)
                         : (row < 128) ? (Wo + (size_t)(row - 64) * HIN)
                                       : (Wg + (size_t)(row - 128) * HIN);
        v = *(const float4*)(src + k);
        dH = WsH + f; dL = WsL + f;
    } else if (idx < 2 * nW) {
        int f = (idx - nW) * 4; int row = f >> 10, k = f & 1023;
        const float* src = (row < 64)  ? (Ui + (size_t)row * HOUT)
                         : (row < 128) ? (Uo + (size_t)(row - 64) * HOUT)
                                       : (Ug + (size_t)(row - 128) * HOUT);
        v = *(const float4*)(src + k);
        dH = UsH + f; dL = UsL + f;
    } else {
        int f = (idx - 2 * nW) * 4;
        if (f >= B_ * HOUT) return;
        v = *(const float4*)(h0 + f);
        int b = f >> 10, c = f & 1023;
        int g = b >> 4, r = b & 15;
        int off = g * 16384 + (c >> 3) * 128 + r * 8 + (c & 7);   // slot 0
        // AGENT-scope stores: write-through to LLC so k_rec's sc0 sc1 reads at t=0
        // never depend on inter-kernel L2 writeback ordering (replay staleness fix).
        unsigned short th[4], tl[4];
        split1(v.x, th[0], tl[0]); split1(v.y, th[1], tl[1]);
        split1(v.z, th[2], tl[2]); split1(v.w, th[3], tl[3]);
        __hip_atomic_store((unsigned*)(hbH + off), (unsigned)th[0] | ((unsigned)th[1] << 16),
                           __ATOMIC_RELAXED, __HIP_MEMORY_SCOPE_AGENT);
        __hip_atomic_store((unsigned*)(hbH + off) + 1, (unsigned)th[2] | ((unsigned)th[3] << 16),
                           __ATOMIC_RELAXED, __HIP_MEMORY_SCOPE_AGENT);
        __hip_atomic_store((unsigned*)(hbL + off), (unsigned)tl[0] | ((unsigned)tl[1] << 16),
                           __ATOMIC_RELAXED, __HIP_MEMORY_SCOPE_AGENT);
        __hip_atomic_store((unsigned*)(hbL + off) + 1, (unsigned)tl[2] | ((unsigned)tl[3] << 16),
                           __ATOMIC_RELAXED, __HIP_MEMORY_SCOPE_AGENT);
        return;
    }
    unsigned short th[4], tl[4];
    split1(v.x, th[0], tl[0]); split1(v.y, th[1], tl[1]);
    split1(v.z, th[2], tl[2]); split1(v.w, th[3], tl[3]);
    *(uint2*)dH = *(const uint2*)th;
    *(uint2*)dL = *(const uint2*)tl;
}

// ---------------- phase 1: gate pre-projection GEMM (bf16x3) ----------------
#define BM 128
#define BN 128
#define BK 32
#define LDP 56

__global__ __launch_bounds__(256) void k_gates(
    const float* __restrict__ x,
    const unsigned short* __restrict__ WsH, const unsigned short* __restrict__ WsL,
    const float* __restrict__ bi, const float* __restrict__ bo, const float* __restrict__ bg,
    float* __restrict__ c_out, float* __restrict__ h_out)
{
    __shared__ unsigned short AlH[BM][LDP], AlL[BM][LDP];
    __shared__ unsigned short BlH[BN][LDP], BlL[BN][LDP];
    const int tid  = threadIdx.x;
    const int bm   = blockIdx.x, bn = blockIdx.y;
    const int wave = tid >> 6,  lane = tid & 63;
    const int l15  = lane & 15, l4 = lane >> 4;
    const int wm   = wave >> 1, wn = wave & 1;
    const int rbase = tid >> 3;          // 0..31
    const int c4    = (tid & 7) * 4;     // 0..28

    f32x4 acc[4][4] = {};

    for (int kk = 0; kk < HIN; kk += BK) {
        #pragma unroll
        for (int i = 0; i < 4; ++i) {
            int row = rbase + 32 * i;
            float4 v = *(const float4*)(x + (size_t)(bm * BM + row) * HIN + kk + c4);
            unsigned short th[4], tl[4];
            split1(v.x, th[0], tl[0]); split1(v.y, th[1], tl[1]);
            split1(v.z, th[2], tl[2]); split1(v.w, th[3], tl[3]);
            *(uint2*)&AlH[row][c4] = *(const uint2*)th;
            *(uint2*)&AlL[row][c4] = *(const uint2*)tl;
            int n = bn * BN + row;
            *(uint2*)&BlH[row][c4] = *(const uint2*)(WsH + (size_t)n * HIN + kk + c4);
            *(uint2*)&BlL[row][c4] = *(const uint2*)(WsL + (size_t)n * HIN + kk + c4);
        }
        __syncthreads();
        uint4 ah[4], al[4], bh4[4], bl4[4];
        #pragma unroll
        for (int mi = 0; mi < 4; ++mi) {
            ah[mi] = *(const uint4*)&AlH[wm * 64 + mi * 16 + l15][l4 * 8];
            al[mi] = *(const uint4*)&AlL[wm * 64 + mi * 16 + l15][l4 * 8];
        }
        #pragma unroll
        for (int ni = 0; ni < 4; ++ni) {
            bh4[ni] = *(const uint4*)&BlH[wn * 64 + ni * 16 + l15][l4 * 8];
            bl4[ni] = *(const uint4*)&BlL[wn * 64 + ni * 16 + l15][l4 * 8];
        }
        #pragma unroll
        for (int mi = 0; mi < 4; ++mi) {
            #pragma unroll
            for (int ni = 0; ni < 4; ++ni) {
                acc[mi][ni] = __builtin_amdgcn_mfma_f32_16x16x32_bf16(
                    __builtin_bit_cast(bf16x8, ah[mi]), __builtin_bit_cast(bf16x8, bh4[ni]),
                    acc[mi][ni], 0, 0, 0);
                acc[mi][ni] = __builtin_amdgcn_mfma_f32_16x16x32_bf16(
                    __builtin_bit_cast(bf16x8, ah[mi]), __builtin_bit_cast(bf16x8, bl4[ni]),
                    acc[mi][ni], 0, 0, 0);
                acc[mi][ni] = __builtin_amdgcn_mfma_f32_16x16x32_bf16(
                    __builtin_bit_cast(bf16x8, al[mi]), __builtin_bit_cast(bf16x8, bh4[ni]),
                    acc[mi][ni], 0, 0, 0);
            }
        }
        __syncthreads();
    }

    #pragma unroll
    for (int ni = 0; ni < 4; ++ni) {
        int n = bn * BN + wn * 64 + ni * 16 + l15;
        float bv = (n < 64) ? bi[n] : (n < 128) ? bo[n - 64] : bg[n - 128];
        #pragma unroll
        for (int mi = 0; mi < 4; ++mi) {
            #pragma unroll
            for (int r = 0; r < 4; ++r) {
                int m = bm * BM + wm * 64 + mi * 16 + l4 * 4 + r;
                float val = acc[mi][ni][r] + bv;
                if (n >= 128) {
                    h_out[(size_t)m * HOUT + (n - 128)] = val;
                } else if (n < 64) {
                    c_out[((size_t)m * NBLK + n) * DBLK + 0] = val;
                } else {
                    c_out[((size_t)m * NBLK + (n - 64)) * DBLK + 1] = val;
                }
            }
        }
    }
}

// ---------------- phase 2: persistent lockstep recurrence (bf16x3) ----------------
// 64 WGs x 256 thr. slice = bid&31, group = bid>>5 (batches [16g,+16)).
// R19 = R18 compute body (fragment-native direct-A, pinned B-hi, LDS B-lo) +
// the R15-PROVEN conservative sync tail (R18's per-wave quarter-flags raced
// when the step got fast enough):
//   publish -> vmcnt(0) -> [B] __syncthreads -> per-WG flag by tid 64 -> outputs.
__global__ __launch_bounds__(256, 1) void k_rec(
    const float* __restrict__ c0,
    float* __restrict__ c_out, float* __restrict__ h_out,
    const unsigned short* __restrict__ UsH, const unsigned short* __restrict__ UsL,
    unsigned short* __restrict__ hbH, unsigned short* __restrict__ hbL,
    unsigned int* __restrict__ flags)
{
    __shared__ unsigned short Wlo[37][1032];   // 74.6 KB (row 36 = zeros)
    __shared__ float preW[4][16][53];          // 13.6 KB per-wave partials (pad 53)

    const int tid   = threadIdx.x;
    const int slice = blockIdx.x & 31;
    const int group = blockIdx.x >> 5;     // 0 or 1
    const int wave  = tid >> 6, lane = tid & 63;
    const int l15   = lane & 15, l4 = lane >> 4;

    // fill Wlo (lo-plane weights) into LDS; row 36 zeroed
    for (int idx = tid; idx < 37 * 128; idx += 256) {
        int row = idx >> 7, c8 = idx & 127;
        uint4 v = make_uint4(0, 0, 0, 0);
        if (row < 36)
            v = *(const uint4*)(UsL + (size_t)slice_row(slice, row) * HOUT + c8 * 8);
        *(uint4*)&Wlo[row][c8 * 8] = v;
    }

    // hi-plane B-fragments for this wave's K-quarter (prologue-pinned, 132-VGPR recipe)
    int wrow[3];
    uint4 bwh[3][8];
    #pragma unroll
    for (int nt = 0; nt < 3; ++nt) {
        int grow = nt * 16 + l15;
        bool valid = grow < 36;
        wrow[nt] = valid ? grow : 36;
        int srow = valid ? slice_row(slice, grow) : 0;
        const unsigned short* ph = UsH + (size_t)srow * HOUT + wave * 256 + l4 * 8;
        #pragma unroll
        for (int ks = 0; ks < 8; ++ks)
            bwh[nt][ks] = valid ? *(const uint4*)(ph + ks * 32) : make_uint4(0, 0, 0, 0);
    }

    // per-thread epilogue mapping: 2 consecutive h-cols
    const int e0   = tid * 2;
    const int bl   = e0 >> 5;             // 0..15 batch-in-group
    const int col0 = e0 & 31;             // even
    const int Bg   = group * 16 + bl;
    const int hcol = slice * 32 + col0;
    const int blkI = hcol >> 4, d0 = hcol & 15;
    float cr0 = c0[((size_t)Bg * NBLK + blkI) * DBLK + d0];
    float cr1 = c0[((size_t)Bg * NBLK + blkI) * DBLK + d0 + 1];

    // publish offset (shorts) within a slot: group/colblk/row/j
    const int puboff = group * 16384 + (slice * 4 + (col0 >> 3)) * 128 + bl * 8 + (col0 & 7);

    unsigned int* flagbase = flags + (size_t)group * NSLICE * 32;
    unsigned int* myflag   = flagbase + slice * 32;                   // per-WG flag, 128B apart
    unsigned int* pollfl   = flagbase + (lane & 31) * 32;

    // A-load base (shorts): unit (colblk = wave*32 + l4, row = l15); ks stride 512 shorts
    const int abase = ((wave * 32 + l4) * 128 + l15 * 8);

    // step-0 gate preactivation prefetch
    float xg0, xg1, xi, xo;
    {
        size_t r0 = (size_t)Bg * S_;
        xg0 = h_out[r0 * HOUT + hcol];
        xg1 = h_out[r0 * HOUT + hcol + 1];
        xi  = c_out[(r0 * NBLK + blkI) * DBLK + 0];
        xo  = c_out[(r0 * NBLK + blkI) * DBLK + 1];
    }

    __syncthreads();   // Wlo ready

    for (int t = 0; t < S_; ++t) {
        // ---- 1. poll (wave 0 only; lanes 0..31 watch the 32 per-WG flags)
        if (t > 0) {
            if (wave == 0) {
                unsigned v;
                do {
                    v = __hip_atomic_load(pollfl, __ATOMIC_RELAXED, __HIP_MEMORY_SCOPE_AGENT);
                } while (!__all((int)(v >= (unsigned)t)));
            }
            __syncthreads();
        }

        // ---- 2. A-fragments straight from LLC: 16 coalesced dwordx4, one drain
        u32x4 ah[8], al[8];
        {
            const char* pH = (const char*)(hbH + (size_t)(t & 1) * 32768
                                           + group * 16384 + abase);
            const char* pL = (const char*)(hbL + (size_t)(t & 1) * 32768
                                           + group * 16384 + abase);
            asm volatile(
                "global_load_dwordx4 %0, %16, off sc0 sc1\n\t"
                "global_load_dwordx4 %1, %16, off offset:1024 sc0 sc1\n\t"
                "global_load_dwordx4 %2, %16, off offset:2048 sc0 sc1\n\t"
                "global_load_dwordx4 %3, %16, off offset:3072 sc0 sc1\n\t"
                "global_load_dwordx4 %4, %17, off sc0 sc1\n\t"
                "global_load_dwordx4 %5, %17, off offset:1024 sc0 sc1\n\t"
                "global_load_dwordx4 %6, %17, off offset:2048 sc0 sc1\n\t"
                "global_load_dwordx4 %7, %17, off offset:3072 sc0 sc1\n\t"
                "global_load_dwordx4 %8, %18, off sc0 sc1\n\t"
                "global_load_dwordx4 %9, %18, off offset:1024 sc0 sc1\n\t"
                "global_load_dwordx4 %10, %18, off offset:2048 sc0 sc1\n\t"
                "global_load_dwordx4 %11, %18, off offset:3072 sc0 sc1\n\t"
                "global_load_dwordx4 %12, %19, off sc0 sc1\n\t"
                "global_load_dwordx4 %13, %19, off offset:1024 sc0 sc1\n\t"
                "global_load_dwordx4 %14, %19, off offset:2048 sc0 sc1\n\t"
                "global_load_dwordx4 %15, %19, off offset:3072 sc0 sc1\n\t"
                "s_waitcnt vmcnt(0)\n\t"
                : "=&v"(ah[0]), "=&v"(ah[1]), "=&v"(ah[2]), "=&v"(ah[3]),
                  "=&v"(ah[4]), "=&v"(ah[5]), "=&v"(ah[6]), "=&v"(ah[7]),
                  "=&v"(al[0]), "=&v"(al[1]), "=&v"(al[2]), "=&v"(al[3]),
                  "=&v"(al[4]), "=&v"(al[5]), "=&v"(al[6]), "=&v"(al[7])
                : "v"(pH), "v"(pH + 4096), "v"(pL), "v"(pL + 4096)
                : "memory");
            __builtin_amdgcn_sched_barrier(0);
        }

        // ---- 3. next-step prefetch (retires during MFMA phase)
        float nxg0 = 0.f, nxg1 = 0.f, nxi = 0.f, nxo = 0.f;
        if (t + 1 < S_) {
            size_t rn = (size_t)Bg * S_ + (t + 1);
            nxg0 = h_out[rn * HOUT + hcol];
            nxg1 = h_out[rn * HOUT + hcol + 1];
            nxi  = c_out[(rn * NBLK + blkI) * DBLK + 0];
            nxo  = c_out[(rn * NBLK + blkI) * DBLK + 1];
        }

        // ---- 4. K-split MFMA: all 36 gate rows over MY quarter
        //         (A direct-loaded; B-hi pinned VGPR; B-lo from LDS)
        f32x4 acc[3] = {};
        #pragma unroll
        for (int ks = 0; ks < 8; ++ks) {
            #pragma unroll
            for (int nt = 0; nt < 3; ++nt) {
                uint4 bl_ = *(const uint4*)&Wlo[wrow[nt]][wave * 256 + ks * 32 + l4 * 8];
                acc[nt] = __builtin_amdgcn_mfma_f32_16x16x32_bf16(
                        __builtin_bit_cast(bf16x8, ah[ks]), __builtin_bit_cast(bf16x8, bwh[nt][ks]), acc[nt], 0, 0, 0);
                acc[nt] = __builtin_amdgcn_mfma_f32_16x16x32_bf16(
                        __builtin_bit_cast(bf16x8, al[ks]), __builtin_bit_cast(bf16x8, bwh[nt][ks]), acc[nt], 0, 0, 0);
                acc[nt] = __builtin_amdgcn_mfma_f32_16x16x32_bf16(
                        __builtin_bit_cast(bf16x8, ah[ks]), __builtin_bit_cast(bf16x8, bl_), acc[nt], 0, 0, 0);
            }
        }

        // ---- 5. per-wave partials to LDS (plain writes; every cell written)
        #pragma unroll
        for (int nt = 0; nt < 3; ++nt) {
            #pragma unroll
            for (int r = 0; r < 4; ++r)
                preW[wave][l4 * 4 + r][nt * 16 + l15] = acc[nt][r];
        }
        __syncthreads();   // [A] all quarters in LDS

        // ---- 6. epilogue: sum 4 wave-partials + prefetched xg/xi/xo
        float gp0 = xg0, gp1 = xg1, ip = xi, op = xo;
        #pragma unroll
        for (int w = 0; w < 4; ++w) {
            gp0 += preW[w][bl][col0];
            gp1 += preW[w][bl][col0 + 1];
            ip  += preW[w][bl][32 + (col0 >> 4)];
            op  += preW[w][bl][34 + (col0 >> 4)];
        }
        float ig  = 1.f / (1.f + __expf(-ip));
        float og  = 1.f / (1.f + __expf(-op));
        cr0 += ig * tanhf(gp0);
        cr1 += ig * tanhf(gp1);
        float h0v = og * tanhf(cr0);
        float h1v = og * tanhf(cr1);

        // ---- 7. publish h_{t+1} -> drain -> [B] barrier -> per-WG flag (tid 64)
        unsigned short h0h, h0l, h1h, h1l;
        split1(h0v, h0h, h0l); split1(h1v, h1h, h1l);
        size_t dsto = (size_t)((t + 1) & 1) * 32768 + puboff;
        __hip_atomic_store((unsigned int*)(hbH + dsto),
                           (unsigned)h0h | ((unsigned)h1h << 16),
                           __ATOMIC_RELAXED, __HIP_MEMORY_SCOPE_AGENT);
        __hip_atomic_store((unsigned int*)(hbL + dsto),
                           (unsigned)h0l | ((unsigned)h1l << 16),
                           __ATOMIC_RELAXED, __HIP_MEMORY_SCOPE_AGENT);

        asm volatile("s_waitcnt vmcnt(0)" ::: "memory");
        __syncthreads();   // [B] ALL waves' publishes drained before the flag
        if (tid == 64)     // flag from wave 1: polling wave stays VMEM-clean
            __hip_atomic_store(myflag, (unsigned)(t + 1),
                               __ATOMIC_RELAXED, __HIP_MEMORY_SCOPE_AGENT);

        // ---- 8. outputs AFTER the flag (RFO latency overlaps next poll)
        size_t ro = (size_t)Bg * S_ + t;
        c_out[(ro * NBLK + blkI) * DBLK + d0]     = cr0;
        c_out[(ro * NBLK + blkI) * DBLK + d0 + 1] = cr1;
        h_out[ro * HOUT + hcol]     = h0v;
        h_out[ro * HOUT + hcol + 1] = h1v;

        // ---- 9. rotate prefetched gate preactivations
        xg0 = nxg0; xg1 = nxg1; xi = nxi; xo = nxo;
    }
}

// ---------------- launch ----------------
extern "C" void kernel_launch(void* const* d_in, const int* in_sizes, int n_in,
                              void* d_out, int out_size, void* d_ws, size_t ws_size,
                              hipStream_t stream) {
    const float* x  = (const float*)d_in[0];
    const float* h0 = (const float*)d_in[1];
    const float* c0 = (const float*)d_in[2];
    const float* Wi = (const float*)d_in[3];
    const float* bi = (const float*)d_in[4];
    const float* Wo = (const float*)d_in[5];
    const float* bo = (const float*)d_in[6];
    const float* Wg = (const float*)d_in[7];
    const float* bg = (const float*)d_in[8];
    const float* Ui = (const float*)d_in[9];
    const float* Uo = (const float*)d_in[10];
    const float* Ug = (const float*)d_in[11];

    float* c_out = (float*)d_out;
    float* h_out = c_out + (size_t)B_ * S_ * NBLK * DBLK;

    unsigned short* WsH  = (unsigned short*)d_ws;                    // [1152][1024]
    unsigned short* WsL  = WsH + (size_t)NGATE * HOUT;
    unsigned short* UsH  = WsL + (size_t)NGATE * HOUT;
    unsigned short* UsL  = UsH + (size_t)NGATE * HOUT;
    unsigned short* hbH  = UsL + (size_t)NGATE * HOUT;               // [2][2][128][16][8]
    unsigned short* hbL  = hbH + (size_t)2 * B_ * HOUT;
    unsigned int*   flags = (unsigned int*)(hbL + (size_t)2 * B_ * HOUT); // [2][32]x128B

    hipMemsetAsync(flags, 0, 64 * 32 * sizeof(unsigned int), stream);
    k_init<<<2336, 256, 0, stream>>>(Wi, Wo, Wg, Ui, Uo, Ug, h0, WsH, WsL, UsH, UsL, hbH, hbL);
    k_gates<<<dim3((B_ * S_) / BM, NGATE / BN), 256, 0, stream>>>(
        x, WsH, WsL, bi, bo, bg, c_out, h_out);
    k_rec<<<64, 256, 0, stream>>>(c0, c_out, h_out, UsH, UsL, hbH, hbL, flags);
}